// Round 2
// baseline (2092.716 us; speedup 1.0000x reference)
//
#include <hip/hip_runtime.h>

#define B 16
#define NN 200000
#define R 1000000
#define ITERS 5
#define E_TOT (8 * R)          // 2/edge (t1) + 3/edge (t2) + 3/edge (t3)
#define SCAN_B 1024

typedef unsigned int uint;

__device__ __forceinline__ float sigmoidf_(float x) {
    return 1.0f / (1.0f + __expf(-x));
}

// ---------------- build phase ----------------

__global__ void cavi_zero_u32(uint* __restrict__ p, int n) {
    int i = blockIdx.x * blockDim.x + threadIdx.x;
    if (i < n) p[i] = 0u;
}

__global__ void cavi_count(const int* __restrict__ i1, const int* __restrict__ i2,
                           const int* __restrict__ i3, uint* __restrict__ cnt) {
    int e = blockIdx.x * blockDim.x + threadIdx.x;
    if (e >= R) return;
    int a1 = i1[2 * e], c1 = i1[2 * e + 1];
    atomicAdd(&cnt[c1], 1u); atomicAdd(&cnt[a1], 1u);
    int a2 = i2[3 * e], b2 = i2[3 * e + 1], c2 = i2[3 * e + 2];
    atomicAdd(&cnt[c2], 1u); atomicAdd(&cnt[a2], 1u); atomicAdd(&cnt[b2], 1u);
    int a3 = i3[3 * e], b3 = i3[3 * e + 1], c3 = i3[3 * e + 2];
    atomicAdd(&cnt[c3], 1u); atomicAdd(&cnt[a3], 1u); atomicAdd(&cnt[b3], 1u);
}

// Block-level exclusive scan; cnt[i] becomes within-block exclusive prefix, bsum[blk]=block total.
__global__ void cavi_scan1(uint* __restrict__ cnt, uint* __restrict__ bsum) {
    __shared__ uint s[SCAN_B];
    int i = blockIdx.x * SCAN_B + threadIdx.x;
    uint v = (i < NN) ? cnt[i] : 0u;
    s[threadIdx.x] = v;
    __syncthreads();
    for (int d = 1; d < SCAN_B; d <<= 1) {
        uint t = (threadIdx.x >= d) ? s[threadIdx.x - d] : 0u;
        __syncthreads();
        s[threadIdx.x] += t;
        __syncthreads();
    }
    if (i < NN) cnt[i] = s[threadIdx.x] - v;
    if (threadIdx.x == SCAN_B - 1) bsum[blockIdx.x] = s[threadIdx.x];
}

// Single block scans the block sums (nb <= 256); bsum[nb] = grand total.
__global__ void cavi_scan2(uint* __restrict__ bsum, int nb) {
    __shared__ uint s[256];
    uint v = (threadIdx.x < (uint)nb) ? bsum[threadIdx.x] : 0u;
    s[threadIdx.x] = v;
    __syncthreads();
    for (int d = 1; d < 256; d <<= 1) {
        uint t = (threadIdx.x >= d) ? s[threadIdx.x - d] : 0u;
        __syncthreads();
        s[threadIdx.x] += t;
        __syncthreads();
    }
    if (threadIdx.x < (uint)nb) bsum[threadIdx.x] = s[threadIdx.x] - v;
    if (threadIdx.x == 255) bsum[nb] = s[255];
}

__global__ void cavi_scan3(const uint* __restrict__ cnt, const uint* __restrict__ bsum,
                           uint* __restrict__ off, uint* __restrict__ cursor, int nb) {
    int i = blockIdx.x * blockDim.x + threadIdx.x;
    if (i < NN) {
        uint v = cnt[i] + bsum[i >> 10];
        off[i] = v;
        cursor[i] = v;
    } else if (i == NN) {
        off[NN] = bsum[nb];
    }
}

__device__ __forceinline__ void put_entry(int dest, int s1, uint md1, int s2, uint md2, float w,
                                          uint* __restrict__ cursor, uint* __restrict__ m0,
                                          uint* __restrict__ m1, float* __restrict__ wf) {
    uint pos = atomicAdd(&cursor[dest], 1u);
    m0[pos] = (uint)s1 | (md1 << 18);
    m1[pos] = (uint)s2 | (md2 << 18);
    wf[pos] = w;
}

// mods: 0 -> x, 1 -> x-1, 2 -> 1-x, 3 -> constant 1 (skip gather)
__global__ void cavi_fill(const int* __restrict__ i1, const float* __restrict__ w1,
                          const int* __restrict__ i2, const float* __restrict__ w2,
                          const int* __restrict__ i3, const float* __restrict__ w3,
                          uint* __restrict__ cursor, uint* __restrict__ m0,
                          uint* __restrict__ m1, float* __restrict__ wf) {
    int e = blockIdx.x * blockDim.x + threadIdx.x;
    if (e >= R) return;
    {   // t1: delta[c] += w*qa ; delta[a] += w*(qc-1)
        int a = i1[2 * e], c = i1[2 * e + 1];
        float w = w1[e];
        put_entry(c, a, 0u, 0, 3u, w, cursor, m0, m1, wf);
        put_entry(a, c, 1u, 0, 3u, w, cursor, m0, m1, wf);
    }
    {   // t2: delta[c] += w*qa*qb ; delta[a] += w*qb*(qc-1) ; delta[b] += w*qa*(qc-1)
        int a = i2[3 * e], b = i2[3 * e + 1], c = i2[3 * e + 2];
        float w = w2[e];
        put_entry(c, a, 0u, b, 0u, w, cursor, m0, m1, wf);
        put_entry(a, b, 0u, c, 1u, w, cursor, m0, m1, wf);
        put_entry(b, a, 0u, c, 1u, w, cursor, m0, m1, wf);
    }
    {   // t3: delta[c] += w*qa*(1-qb) ; delta[a] += w*(1-qb)*(qc-1) ; delta[b] += w*qa*(1-qc)
        int a = i3[3 * e], b = i3[3 * e + 1], c = i3[3 * e + 2];
        float w = w3[e];
        put_entry(c, a, 0u, b, 2u, w, cursor, m0, m1, wf);
        put_entry(a, b, 2u, c, 1u, w, cursor, m0, m1, wf);
        put_entry(b, a, 0u, c, 2u, w, cursor, m0, m1, wf);
    }
}

// ---------------- init / finish transposes ----------------

// ev [B][N] -> ev_nb [N][B]; logits_nb = ev_nb; q0 = sigmoid(ev)
__global__ void cavi_init_tp(const float* __restrict__ ev, float* __restrict__ ev_nb,
                             float* __restrict__ logits_nb, float* __restrict__ q0) {
    __shared__ float lds[64 * 17];
    int n0 = blockIdx.x * 64;   // NN % 64 == 0 -> 3125 exact blocks
    #pragma unroll
    for (int p = 0; p < 4; ++p) {
        int idx = p * 256 + threadIdx.x;     // b-major
        int b = idx >> 6, i = idx & 63;
        lds[i * 17 + b] = ev[b * NN + n0 + i];
    }
    __syncthreads();
    #pragma unroll
    for (int p = 0; p < 4; ++p) {
        int j = p * 256 + threadIdx.x;       // j = i*16 + b
        int i = j >> 4, b = j & 15;
        float v = lds[i * 17 + b];
        int o = n0 * B + j;
        ev_nb[o] = v;
        logits_nb[o] = v;
        q0[o] = sigmoidf_(v);
    }
}

// q_nb [N][B] -> out [B][N]
__global__ void cavi_out_tp(const float* __restrict__ q_nb, float* __restrict__ out) {
    __shared__ float lds[64 * 17];
    int n0 = blockIdx.x * 64;
    #pragma unroll
    for (int p = 0; p < 4; ++p) {
        int j = p * 256 + threadIdx.x;       // j = i*16 + b
        int i = j >> 4, b = j & 15;
        lds[i * 17 + b] = q_nb[n0 * B + j];
    }
    __syncthreads();
    #pragma unroll
    for (int p = 0; p < 4; ++p) {
        int idx = p * 256 + threadIdx.x;     // b-major
        int b = idx >> 6, i = idx & 63;
        out[b * NN + n0 + i] = lds[i * 17 + b];
    }
}

// ---------------- main fused iteration ----------------

__global__ void cavi_main(const uint* __restrict__ off,
                          const uint* __restrict__ m0, const uint* __restrict__ m1,
                          const float* __restrict__ wf,
                          const float* __restrict__ ev_nb, float* __restrict__ logits_nb,
                          const float* __restrict__ q_in, float* __restrict__ q_out) {
    int t = blockIdx.x * blockDim.x + threadIdx.x;
    if (t >= NN * B) return;
    int n = t >> 4, b = t & 15;
    uint k0 = off[n], k1 = off[n + 1];
    float acc = 0.0f;
    for (uint k = k0; k < k1; ++k) {
        uint a0 = m0[k], a1 = m1[k];
        float w = wf[k];
        float x = q_in[((a0 & 0x3FFFFu) << 4) + b];
        uint md1 = a0 >> 18;
        x = (md1 == 0u) ? x : ((md1 == 1u) ? x - 1.0f : 1.0f - x);
        uint md2 = a1 >> 18;
        float y = 1.0f;
        if (md2 != 3u) {
            float q2 = q_in[((a1 & 0x3FFFFu) << 4) + b];
            y = (md2 == 0u) ? q2 : ((md2 == 1u) ? q2 - 1.0f : 1.0f - q2);
        }
        acc = fmaf(w * x, y, acc);
    }
    float nl = 0.5f * logits_nb[t] + 0.5f * (ev_nb[t] + acc);
    logits_nb[t] = nl;
    q_out[t] = sigmoidf_(nl);
}

// ---------------- fallback (round-1 atomic path) ----------------

__global__ void fb_init(const float* __restrict__ ev, float* __restrict__ logits,
                        float* __restrict__ q_nb, float* __restrict__ delta_nb) {
    int i = blockIdx.x * blockDim.x + threadIdx.x;
    if (i >= NN * B) return;
    int b = i & 15, n = i >> 4;
    float e = ev[b * NN + n];
    logits[b * NN + n] = e;
    q_nb[i] = sigmoidf_(e);
    delta_nb[i] = 0.0f;
}

__global__ void fb_edges(const float* __restrict__ q, float* __restrict__ delta,
                         const int* __restrict__ idx1, const float* __restrict__ w1,
                         const int* __restrict__ idx2, const float* __restrict__ w2,
                         const int* __restrict__ idx3, const float* __restrict__ w3) {
    int gid = blockIdx.x * blockDim.x + threadIdx.x;
    int b = gid & 15;
    int e = gid >> 4;
    if (e >= 3 * R) return;
    if (e < R) {
        int a = idx1[e * 2 + 0], c = idx1[e * 2 + 1];
        float w = w1[e];
        float qa = q[a * B + b], qc = q[c * B + b];
        atomicAdd(&delta[c * B + b], w * qa);
        atomicAdd(&delta[a * B + b], w * (qc - 1.0f));
    } else if (e < 2 * R) {
        int ei = e - R;
        int a = idx2[ei * 3], bb = idx2[ei * 3 + 1], c = idx2[ei * 3 + 2];
        float w = w2[ei];
        float qa = q[a * B + b], qb = q[bb * B + b], qc = q[c * B + b];
        atomicAdd(&delta[c * B + b], w * qa * qb);
        atomicAdd(&delta[a * B + b], w * qb * (qc - 1.0f));
        atomicAdd(&delta[bb * B + b], w * qa * (qc - 1.0f));
    } else {
        int ei = e - 2 * R;
        int a = idx3[ei * 3], bb = idx3[ei * 3 + 1], c = idx3[ei * 3 + 2];
        float w = w3[ei];
        float qa = q[a * B + b], qb = q[bb * B + b], qc = q[c * B + b];
        atomicAdd(&delta[c * B + b], w * qa * (1.0f - qb));
        atomicAdd(&delta[a * B + b], w * (1.0f - qb) * (qc - 1.0f));
        atomicAdd(&delta[bb * B + b], w * qa * (1.0f - qc));
    }
}

__global__ void fb_update(const float* __restrict__ ev, float* __restrict__ logits,
                          float* __restrict__ q_nb, float* __restrict__ delta_nb, int write_q) {
    int i = blockIdx.x * blockDim.x + threadIdx.x;
    if (i >= NN * B) return;
    int b = i & 15, n = i >> 4;
    float d = delta_nb[i];
    delta_nb[i] = 0.0f;
    float e = ev[b * NN + n];
    float cl = logits[b * NN + n];
    float nl = 0.5f * cl + 0.5f * (e + d);
    float qv = sigmoidf_(nl);
    q_nb[i] = qv;
    logits[b * NN + n] = write_q ? qv : nl;
}

// ---------------- launch ----------------

extern "C" void kernel_launch(void* const* d_in, const int* in_sizes, int n_in,
                              void* d_out, int out_size, void* d_ws, size_t ws_size,
                              hipStream_t stream) {
    const float* ev = (const float*)d_in[0];
    const float* w1 = (const float*)d_in[1];
    const float* w2 = (const float*)d_in[2];
    const float* w3 = (const float*)d_in[3];
    const int* i1 = (const int*)d_in[4];
    const int* i2 = (const int*)d_in[5];
    const int* i3 = (const int*)d_in[6];

    const size_t NB = (size_t)NN * B;

    // workspace layout for CSR path
    float* ev_nb = (float*)d_ws;
    float* logits_nb = ev_nb + NB;
    float* q0 = logits_nb + NB;
    float* q1 = q0 + NB;
    uint* cnt = (uint*)(q1 + NB);
    uint* off = cnt + NN;
    uint* cursor = off + (NN + 1);
    uint* bsum = cursor + NN;           // 256+2 slots
    uint* m0 = bsum + 272;
    uint* m1 = m0 + (size_t)E_TOT;
    float* wf = (float*)(m1 + (size_t)E_TOT);
    size_t needed = (size_t)((char*)(wf + (size_t)E_TOT) - (char*)d_ws);

    if (ws_size < needed) {
        // fallback: round-1 atomic path (needs 2*NB floats)
        float* logits = (float*)d_out;
        float* q_nb = (float*)d_ws;
        float* delta_nb = q_nb + NB;
        const int th = 256;
        const int nbg = (int)((NB + th - 1) / th);
        const int eg = (3 * R * B + th - 1) / th;
        fb_init<<<nbg, th, 0, stream>>>(ev, logits, q_nb, delta_nb);
        for (int it = 0; it < ITERS; ++it) {
            fb_edges<<<eg, th, 0, stream>>>(q_nb, delta_nb, i1, w1, i2, w2, i3, w3);
            fb_update<<<nbg, th, 0, stream>>>(ev, logits, q_nb, delta_nb, it == ITERS - 1 ? 1 : 0);
        }
        return;
    }

    const int th = 256;
    const int scan_blocks = (NN + SCAN_B - 1) / SCAN_B;   // 196

    // build CSR (per call; deterministic work)
    cavi_zero_u32<<<(NN + th - 1) / th, th, 0, stream>>>(cnt, NN);
    cavi_count<<<(R + th - 1) / th, th, 0, stream>>>(i1, i2, i3, cnt);
    cavi_scan1<<<scan_blocks, SCAN_B, 0, stream>>>(cnt, bsum);
    cavi_scan2<<<1, 256, 0, stream>>>(bsum, scan_blocks);
    cavi_scan3<<<(NN + 1 + th) / th, th, 0, stream>>>(cnt, bsum, off, cursor, scan_blocks);
    cavi_fill<<<(R + th - 1) / th, th, 0, stream>>>(i1, w1, i2, w2, i3, w3, cursor, m0, m1, wf);

    // init state
    cavi_init_tp<<<NN / 64, 256, 0, stream>>>(ev, ev_nb, logits_nb, q0);

    // iterate
    const int mg = (int)(NB / th);      // 12500 exact
    float* qi = q0;
    float* qo = q1;
    for (int it = 0; it < ITERS; ++it) {
        cavi_main<<<mg, th, 0, stream>>>(off, m0, m1, wf, ev_nb, logits_nb, qi, qo);
        float* tmp = qi; qi = qo; qo = tmp;
    }

    // qi now holds the final q
    cavi_out_tp<<<NN / 64, 256, 0, stream>>>(qi, (float*)d_out);
}

// Round 3
// 2078.021 us; speedup vs baseline: 1.0071x; 1.0071x over previous
//
#include <hip/hip_runtime.h>
#include <hip/hip_fp16.h>

#define B 16
#define NN 200000
#define R 1000000
#define ITERS 5
#define E_TOT (8 * R)          // 2/edge (t1) + 3/edge (t2) + 3/edge (t3)
#define SCAN_B 1024

typedef unsigned int uint;
typedef unsigned short ushort;

__device__ __forceinline__ float sigmoidf_(float x) {
    return 1.0f / (1.0f + __expf(-x));
}

// ---------------- build phase ----------------

__global__ void cavi_zero_u32(uint* __restrict__ p, int n) {
    int i = blockIdx.x * blockDim.x + threadIdx.x;
    if (i < n) p[i] = 0u;
}

__global__ void cavi_count(const int* __restrict__ i1, const int* __restrict__ i2,
                           const int* __restrict__ i3, uint* __restrict__ cnt) {
    int e = blockIdx.x * blockDim.x + threadIdx.x;
    if (e >= R) return;
    int a1 = i1[2 * e], c1 = i1[2 * e + 1];
    atomicAdd(&cnt[c1], 1u); atomicAdd(&cnt[a1], 1u);
    int a2 = i2[3 * e], b2 = i2[3 * e + 1], c2 = i2[3 * e + 2];
    atomicAdd(&cnt[c2], 1u); atomicAdd(&cnt[a2], 1u); atomicAdd(&cnt[b2], 1u);
    int a3 = i3[3 * e], b3 = i3[3 * e + 1], c3 = i3[3 * e + 2];
    atomicAdd(&cnt[c3], 1u); atomicAdd(&cnt[a3], 1u); atomicAdd(&cnt[b3], 1u);
}

// Block-level exclusive scan; cnt[i] becomes within-block exclusive prefix, bsum[blk]=block total.
__global__ void cavi_scan1(uint* __restrict__ cnt, uint* __restrict__ bsum) {
    __shared__ uint s[SCAN_B];
    int i = blockIdx.x * SCAN_B + threadIdx.x;
    uint v = (i < NN) ? cnt[i] : 0u;
    s[threadIdx.x] = v;
    __syncthreads();
    for (int d = 1; d < SCAN_B; d <<= 1) {
        uint t = (threadIdx.x >= d) ? s[threadIdx.x - d] : 0u;
        __syncthreads();
        s[threadIdx.x] += t;
        __syncthreads();
    }
    if (i < NN) cnt[i] = s[threadIdx.x] - v;
    if (threadIdx.x == SCAN_B - 1) bsum[blockIdx.x] = s[threadIdx.x];
}

// Single block scans the block sums (nb <= 256); bsum[nb] = grand total.
__global__ void cavi_scan2(uint* __restrict__ bsum, int nb) {
    __shared__ uint s[256];
    uint v = (threadIdx.x < (uint)nb) ? bsum[threadIdx.x] : 0u;
    s[threadIdx.x] = v;
    __syncthreads();
    for (int d = 1; d < 256; d <<= 1) {
        uint t = (threadIdx.x >= d) ? s[threadIdx.x - d] : 0u;
        __syncthreads();
        s[threadIdx.x] += t;
        __syncthreads();
    }
    if (threadIdx.x < (uint)nb) bsum[threadIdx.x] = s[threadIdx.x] - v;
    if (threadIdx.x == 255) bsum[nb] = s[255];
}

__global__ void cavi_scan3(const uint* __restrict__ cnt, const uint* __restrict__ bsum,
                           uint* __restrict__ off, uint* __restrict__ cursor, int nb) {
    int i = blockIdx.x * blockDim.x + threadIdx.x;
    if (i < NN) {
        uint v = cnt[i] + bsum[i >> 10];
        off[i] = v;
        cursor[i] = v;
    } else if (i == NN) {
        off[NN] = bsum[nb];
    }
}

// Entry packing (8 B): lo = src1(0..17) | md1(18..19) | src2_lo12(20..31)
//                      hi = src2_hi6(0..5) | md2(6..7) | fp16 w(16..31)
__device__ __forceinline__ void put_entry(int dest, int s1, uint md1, int s2, uint md2, float w,
                                          uint* __restrict__ cursor, uint2* __restrict__ ent) {
    uint pos = atomicAdd(&cursor[dest], 1u);
    uint lo = (uint)s1 | (md1 << 18) | (((uint)s2 & 0xFFFu) << 20);
    uint hi = ((uint)s2 >> 12) | (md2 << 6)
            | ((uint)__half_as_ushort(__float2half(w)) << 16);
    ent[pos] = make_uint2(lo, hi);
}

// mods: 0 -> x, 1 -> x-1, 2 -> 1-x, 3 -> constant 1
__global__ void cavi_fill(const int* __restrict__ i1, const float* __restrict__ w1,
                          const int* __restrict__ i2, const float* __restrict__ w2,
                          const int* __restrict__ i3, const float* __restrict__ w3,
                          uint* __restrict__ cursor, uint2* __restrict__ ent) {
    int e = blockIdx.x * blockDim.x + threadIdx.x;
    if (e >= R) return;
    {   // t1: delta[c] += w*qa ; delta[a] += w*(qc-1)
        int a = i1[2 * e], c = i1[2 * e + 1];
        float w = w1[e];
        put_entry(c, a, 0u, 0, 3u, w, cursor, ent);
        put_entry(a, c, 1u, 0, 3u, w, cursor, ent);
    }
    {   // t2: delta[c] += w*qa*qb ; delta[a] += w*qb*(qc-1) ; delta[b] += w*qa*(qc-1)
        int a = i2[3 * e], b = i2[3 * e + 1], c = i2[3 * e + 2];
        float w = w2[e];
        put_entry(c, a, 0u, b, 0u, w, cursor, ent);
        put_entry(a, b, 0u, c, 1u, w, cursor, ent);
        put_entry(b, a, 0u, c, 1u, w, cursor, ent);
    }
    {   // t3: delta[c] += w*qa*(1-qb) ; delta[a] += w*(1-qb)*(qc-1) ; delta[b] += w*qa*(1-qc)
        int a = i3[3 * e], b = i3[3 * e + 1], c = i3[3 * e + 2];
        float w = w3[e];
        put_entry(c, a, 0u, b, 2u, w, cursor, ent);
        put_entry(a, b, 2u, c, 1u, w, cursor, ent);
        put_entry(b, a, 0u, c, 2u, w, cursor, ent);
    }
}

// ---------------- init / finish transposes ----------------

// ev [B][N] -> ev_nb [N][B] (f32); logits_nb = ev_nb (f32); q0 = sigmoid(ev) (fp16)
__global__ void cavi_init_tp(const float* __restrict__ ev, float* __restrict__ ev_nb,
                             float* __restrict__ logits_nb, __half* __restrict__ q0) {
    __shared__ float lds[64 * 17];
    int n0 = blockIdx.x * 64;   // NN % 64 == 0 -> 3125 exact blocks
    #pragma unroll
    for (int p = 0; p < 4; ++p) {
        int idx = p * 256 + threadIdx.x;     // b-major
        int b = idx >> 6, i = idx & 63;
        lds[i * 17 + b] = ev[b * NN + n0 + i];
    }
    __syncthreads();
    #pragma unroll
    for (int p = 0; p < 4; ++p) {
        int j = p * 256 + threadIdx.x;       // j = i*16 + b
        int i = j >> 4, b = j & 15;
        float v = lds[i * 17 + b];
        int o = n0 * B + j;
        ev_nb[o] = v;
        logits_nb[o] = v;
        q0[o] = __float2half(sigmoidf_(v));
    }
}

// q_nb [N][B] fp16 -> out [B][N] f32
__global__ void cavi_out_tp(const __half* __restrict__ q_nb, float* __restrict__ out) {
    __shared__ float lds[64 * 17];
    int n0 = blockIdx.x * 64;
    #pragma unroll
    for (int p = 0; p < 4; ++p) {
        int j = p * 256 + threadIdx.x;       // j = i*16 + b
        int i = j >> 4, b = j & 15;
        lds[i * 17 + b] = __half2float(q_nb[n0 * B + j]);
    }
    __syncthreads();
    #pragma unroll
    for (int p = 0; p < 4; ++p) {
        int idx = p * 256 + threadIdx.x;     // b-major
        int b = idx >> 6, i = idx & 63;
        out[b * NN + n0 + i] = lds[i * 17 + b];
    }
}

// ---------------- main fused iteration ----------------

__device__ __forceinline__ float ent_term(uint lo, uint hi, int b,
                                          const __half* __restrict__ q_in) {
    int s1 = (int)(lo & 0x3FFFFu);
    uint md1 = (lo >> 18) & 3u;
    int s2 = (int)(((lo >> 20) & 0xFFFu) | ((hi & 0x3Fu) << 12));
    uint md2 = (hi >> 6) & 3u;
    float w = __half2float(__ushort_as_half((ushort)(hi >> 16)));
    float x = __half2float(q_in[(s1 << 4) + b]);
    x = (md1 == 0u) ? x : ((md1 == 1u) ? x - 1.0f : 1.0f - x);
    float q2 = __half2float(q_in[(s2 << 4) + b]);   // s2==0 for t1, harmless
    float y = (md2 == 0u) ? q2 : ((md2 == 1u) ? q2 - 1.0f : ((md2 == 2u) ? 1.0f - q2 : 1.0f));
    return w * x * y;
}

__global__ __launch_bounds__(256) void cavi_main(
        const uint* __restrict__ off, const uint2* __restrict__ ent,
        const float* __restrict__ ev_nb, float* __restrict__ logits_nb,
        const __half* __restrict__ q_in, __half* __restrict__ q_out) {
    int t = blockIdx.x * blockDim.x + threadIdx.x;
    if (t >= NN * B) return;
    int n = t >> 4, b = t & 15;
    uint k0 = off[n], k1 = off[n + 1];
    float acc = 0.0f;
    uint k = k0;
    for (; k + 2 <= k1; k += 2) {
        uint2 e0 = ent[k];
        uint2 e1 = ent[k + 1];
        acc += ent_term(e0.x, e0.y, b, q_in);
        acc += ent_term(e1.x, e1.y, b, q_in);
    }
    if (k < k1) {
        uint2 e0 = ent[k];
        acc += ent_term(e0.x, e0.y, b, q_in);
    }
    float nl = 0.5f * logits_nb[t] + 0.5f * (ev_nb[t] + acc);
    logits_nb[t] = nl;
    q_out[t] = __float2half(sigmoidf_(nl));
}

// ---------------- fallback (round-1 atomic path) ----------------

__global__ void fb_init(const float* __restrict__ ev, float* __restrict__ logits,
                        float* __restrict__ q_nb, float* __restrict__ delta_nb) {
    int i = blockIdx.x * blockDim.x + threadIdx.x;
    if (i >= NN * B) return;
    int b = i & 15, n = i >> 4;
    float e = ev[b * NN + n];
    logits[b * NN + n] = e;
    q_nb[i] = sigmoidf_(e);
    delta_nb[i] = 0.0f;
}

__global__ void fb_edges(const float* __restrict__ q, float* __restrict__ delta,
                         const int* __restrict__ idx1, const float* __restrict__ w1,
                         const int* __restrict__ idx2, const float* __restrict__ w2,
                         const int* __restrict__ idx3, const float* __restrict__ w3) {
    int gid = blockIdx.x * blockDim.x + threadIdx.x;
    int b = gid & 15;
    int e = gid >> 4;
    if (e >= 3 * R) return;
    if (e < R) {
        int a = idx1[e * 2 + 0], c = idx1[e * 2 + 1];
        float w = w1[e];
        float qa = q[a * B + b], qc = q[c * B + b];
        atomicAdd(&delta[c * B + b], w * qa);
        atomicAdd(&delta[a * B + b], w * (qc - 1.0f));
    } else if (e < 2 * R) {
        int ei = e - R;
        int a = idx2[ei * 3], bb = idx2[ei * 3 + 1], c = idx2[ei * 3 + 2];
        float w = w2[ei];
        float qa = q[a * B + b], qb = q[bb * B + b], qc = q[c * B + b];
        atomicAdd(&delta[c * B + b], w * qa * qb);
        atomicAdd(&delta[a * B + b], w * qb * (qc - 1.0f));
        atomicAdd(&delta[bb * B + b], w * qa * (qc - 1.0f));
    } else {
        int ei = e - 2 * R;
        int a = idx3[ei * 3], bb = idx3[ei * 3 + 1], c = idx3[ei * 3 + 2];
        float w = w3[ei];
        float qa = q[a * B + b], qb = q[bb * B + b], qc = q[c * B + b];
        atomicAdd(&delta[c * B + b], w * qa * (1.0f - qb));
        atomicAdd(&delta[a * B + b], w * (1.0f - qb) * (qc - 1.0f));
        atomicAdd(&delta[bb * B + b], w * qa * (1.0f - qc));
    }
}

__global__ void fb_update(const float* __restrict__ ev, float* __restrict__ logits,
                          float* __restrict__ q_nb, float* __restrict__ delta_nb, int write_q) {
    int i = blockIdx.x * blockDim.x + threadIdx.x;
    if (i >= NN * B) return;
    int b = i & 15, n = i >> 4;
    float d = delta_nb[i];
    delta_nb[i] = 0.0f;
    float e = ev[b * NN + n];
    float cl = logits[b * NN + n];
    float nl = 0.5f * cl + 0.5f * (e + d);
    float qv = sigmoidf_(nl);
    q_nb[i] = qv;
    logits[b * NN + n] = write_q ? qv : nl;
}

// ---------------- launch ----------------

extern "C" void kernel_launch(void* const* d_in, const int* in_sizes, int n_in,
                              void* d_out, int out_size, void* d_ws, size_t ws_size,
                              hipStream_t stream) {
    const float* ev = (const float*)d_in[0];
    const float* w1 = (const float*)d_in[1];
    const float* w2 = (const float*)d_in[2];
    const float* w3 = (const float*)d_in[3];
    const int* i1 = (const int*)d_in[4];
    const int* i2 = (const int*)d_in[5];
    const int* i3 = (const int*)d_in[6];

    const size_t NB = (size_t)NN * B;

    // workspace layout (entries first for 8B alignment)
    uint2* ent = (uint2*)d_ws;                       // 8M * 8B = 64 MB
    float* ev_nb = (float*)(ent + (size_t)E_TOT);    // 12.8 MB
    float* logits_nb = ev_nb + NB;                   // 12.8 MB
    __half* q0 = (__half*)(logits_nb + NB);          // 6.4 MB
    __half* q1 = q0 + NB;                            // 6.4 MB
    uint* cnt = (uint*)(q1 + NB);
    uint* off = cnt + NN;
    uint* cursor = off + (NN + 1);
    uint* bsum = cursor + NN;                        // 256+2 slots
    size_t needed = (size_t)((char*)(bsum + 272) - (char*)d_ws);

    if (ws_size < needed) {
        // fallback: round-1 atomic path (needs 2*NB floats)
        float* logits = (float*)d_out;
        float* q_nb = (float*)d_ws;
        float* delta_nb = q_nb + NB;
        const int th = 256;
        const int nbg = (int)((NB + th - 1) / th);
        const int eg = (3 * R * B + th - 1) / th;
        fb_init<<<nbg, th, 0, stream>>>(ev, logits, q_nb, delta_nb);
        for (int it = 0; it < ITERS; ++it) {
            fb_edges<<<eg, th, 0, stream>>>(q_nb, delta_nb, i1, w1, i2, w2, i3, w3);
            fb_update<<<nbg, th, 0, stream>>>(ev, logits, q_nb, delta_nb, it == ITERS - 1 ? 1 : 0);
        }
        return;
    }

    const int th = 256;
    const int scan_blocks = (NN + SCAN_B - 1) / SCAN_B;   // 196

    // build CSR (per call; deterministic work)
    cavi_zero_u32<<<(NN + th - 1) / th, th, 0, stream>>>(cnt, NN);
    cavi_count<<<(R + th - 1) / th, th, 0, stream>>>(i1, i2, i3, cnt);
    cavi_scan1<<<scan_blocks, SCAN_B, 0, stream>>>(cnt, bsum);
    cavi_scan2<<<1, 256, 0, stream>>>(bsum, scan_blocks);
    cavi_scan3<<<(NN + 1 + th) / th, th, 0, stream>>>(cnt, bsum, off, cursor, scan_blocks);
    cavi_fill<<<(R + th - 1) / th, th, 0, stream>>>(i1, w1, i2, w2, i3, w3, cursor, ent);

    // init state
    cavi_init_tp<<<NN / 64, 256, 0, stream>>>(ev, ev_nb, logits_nb, q0);

    // iterate
    const int mg = (int)(NB / th);      // 12500 exact
    __half* qi = q0;
    __half* qo = q1;
    for (int it = 0; it < ITERS; ++it) {
        cavi_main<<<mg, th, 0, stream>>>(off, ent, ev_nb, logits_nb, qi, qo);
        __half* tmp = qi; qi = qo; qo = tmp;
    }

    // qi now holds the final q
    cavi_out_tp<<<NN / 64, 256, 0, stream>>>(qi, (float*)d_out);
}